// Round 2
// baseline (277.098 us; speedup 1.0000x reference)
//
#include <hip/hip_runtime.h>

// SimVQuantizer: B=8, D=128 (N_CB=8 x CDIM=16), H=W=32 -> 8192 pixels.
// Outputs (FLOAT32, concatenated flat):
//   quantized  [8,128,32,32]  = 1048576   @ 0
//   indices    [8,8,32,32]    =   65536   @ 1048576
//   commitment scalar         =       1   @ 1114112
//   new_codebooks [8,1024,16] =  131072   @ 1114113
//   new_count  [8,1024]       =    8192   @ 1245185
//   new_weight [8,1024,16]    =  131072   @ 1253377
// total 1384449

#define NCB   8
#define VOCAB 1024
#define CDIM  16
#define NPIX  8192   // B*H*W
#define HW    1024   // H*W

#define OFF_QUANT  0
#define OFF_IDX    1048576
#define OFF_COMMIT 1114112
#define OFF_NCB    1114113
#define OFF_NCNT   1245185
#define OFF_NWT    1253377

// workspace layout (floats): counts[8*1024], sums[8*1024*16], then a double
#define WS_COUNTS_OFF 0
#define WS_SUMS_OFF   (NCB * VOCAB)
#define WS_COMMIT_BYTE_OFF (size_t)((NCB * VOCAB) * 4 + (NCB * VOCAB * CDIM) * 4) // 557056
#define WS_ZERO_BYTES (WS_COMMIT_BYTE_OFF + 8)

// numpy pairwise_sum (order-preserving 8-accumulator) for n=16:
// r[j] = a[j] + a[j+8];  res = ((r0+r1)+(r2+r3)) + ((r4+r5)+(r6+r7))
__device__ __forceinline__ float npsum16(const float m[16]) {
#pragma clang fp contract(off)
  float r0 = m[0] + m[8];
  float r1 = m[1] + m[9];
  float r2 = m[2] + m[10];
  float r3 = m[3] + m[11];
  float r4 = m[4] + m[12];
  float r5 = m[5] + m[13];
  float r6 = m[6] + m[14];
  float r7 = m[7] + m[15];
  return ((r0 + r1) + (r2 + r3)) + ((r4 + r5) + (r6 + r7));
}

__device__ __forceinline__ float npsum16sq(const float a[16]) {
#pragma clang fp contract(off)
  float m[16];
#pragma unroll
  for (int d = 0; d < 16; ++d) m[d] = a[d] * a[d];
  return npsum16(m);
}

// numpy einsum (optimize=False) SSE3/npyv contig_two order for n=16:
// 4 lane-strided partials l_j = (m_j + m_{j+4}) + (m_{j+8} + m_{j+12}),
// horizontal hadd: (l0+l1) + (l2+l3). No FMA.
__device__ __forceinline__ float npeinsum16(const float a[16], const float b[16]) {
#pragma clang fp contract(off)
  float m[16];
#pragma unroll
  for (int d = 0; d < 16; ++d) m[d] = a[d] * b[d];
  float l0 = (m[0] + m[4]) + (m[8] + m[12]);
  float l1 = (m[1] + m[5]) + (m[9] + m[13]);
  float l2 = (m[2] + m[6]) + (m[10] + m[14]);
  float l3 = (m[3] + m[7]) + (m[11] + m[15]);
  return (l0 + l1) + (l2 + l3);
}

// One thread = one (pixel, codebook) pair. 256 blocks x 256 threads.
// blockIdx: c = blk>>5 (8 codebooks), chunk = blk&31 (32 chunks of 256 pixels).
__global__ __launch_bounds__(256) void k_assign(
    const float* __restrict__ z, const float* __restrict__ cb,
    float* __restrict__ out, float* __restrict__ ws_counts,
    float* __restrict__ ws_sums, double* __restrict__ ws_commit) {
  __shared__ float s_c2[VOCAB];
  __shared__ float s_part[4];

  const int c = blockIdx.x >> 5;
  const int chunk = blockIdx.x & 31;
  const int t = threadIdx.x;

  const float* cbc = cb + (size_t)c * VOCAB * CDIM;

  // precompute ||cb||^2 into LDS (np.sum(cb*cb, -1), pairwise 8-acc order)
  for (int v = t; v < VOCAB; v += 256) {
    float e[16];
#pragma unroll
    for (int d = 0; d < 16; ++d) e[d] = cbc[(size_t)v * CDIM + d];
    s_c2[v] = npsum16sq(e);
  }
  __syncthreads();

  const int n = chunk * 256 + t;   // pixel id in [0, 8192)
  const int b = n >> 10;           // batch
  const int hw = n & 1023;         // h*W + w

  // zp[n,c,d] = z[b, c*16+d, h, w]; stride across d is HW floats
  const float* zbase = z + ((size_t)(b * 128 + c * 16)) * HW + hw;
  float zv[16];
#pragma unroll
  for (int d = 0; d < 16; ++d) zv[d] = zbase[(size_t)d * HW];

  const float z2 = npsum16sq(zv);

  float best = INFINITY;
  int bi = 0;
#pragma unroll 4
  for (int v = 0; v < VOCAB; ++v) {
    // block-uniform address -> scalar loads (entry shared by the wave)
    float e[16];
    const float4* e4 = reinterpret_cast<const float4*>(cbc + (size_t)v * CDIM);
    float4 q0 = e4[0], q1 = e4[1], q2 = e4[2], q3 = e4[3];
    e[0] = q0.x; e[1] = q0.y; e[2] = q0.z; e[3] = q0.w;
    e[4] = q1.x; e[5] = q1.y; e[6] = q1.z; e[7] = q1.w;
    e[8] = q2.x; e[9] = q2.y; e[10] = q2.z; e[11] = q2.w;
    e[12] = q3.x; e[13] = q3.y; e[14] = q3.z; e[15] = q3.w;
    const float dot = npeinsum16(zv, e);
    float d2;
    {
#pragma clang fp contract(off)
      d2 = (z2 - 2.0f * dot) + s_c2[v];  // np order: (z2 - 2*einsum) + c2
    }
    const bool lt = d2 < best;   // strict: first index wins ties (np.argmin)
    best = lt ? d2 : best;
    bi = lt ? v : bi;
  }

  // gather selected codebook entry, write quantized + commitment terms
  const float* qe = cbc + (size_t)bi * CDIM;
  float comm = 0.f;
#pragma unroll
  for (int d = 0; d < 16; ++d) {
    float zq = qe[d];
    float diff, qst;
    {
#pragma clang fp contract(off)
      diff = zv[d] - zq;
      qst = zv[d] + (zq - zv[d]);  // zq_st = zp + (zq - zp), as np computes it
    }
    comm += diff * diff;
    out[OFF_QUANT + ((size_t)(b * 128 + c * 16 + d)) * HW + hw] = qst;
  }
  out[OFF_IDX + ((size_t)(b * NCB + c)) * HW + hw] = (float)bi;

  // scatter: counts and sums (EMA statistics). Counts are exact integers.
  atomicAdd(&ws_counts[c * VOCAB + bi], 1.0f);
#pragma unroll
  for (int d = 0; d < 16; ++d)
    atomicAdd(&ws_sums[((size_t)(c * VOCAB + bi)) * CDIM + d], zv[d]);

  // commitment: wave reduce -> block reduce -> one f64 atomic per block
#pragma unroll
  for (int off = 32; off; off >>= 1) comm += __shfl_down(comm, off);
  if ((t & 63) == 0) s_part[t >> 6] = comm;
  __syncthreads();
  if (t == 0) {
    float tot = (s_part[0] + s_part[1]) + (s_part[2] + s_part[3]);
    atomicAdd(ws_commit, (double)tot);
  }
}

// EMA update + Laplace-smoothed normalization. 8 blocks (one per codebook).
__global__ __launch_bounds__(256) void k_update(
    const float* __restrict__ ema_count, const float* __restrict__ ema_weight,
    const float* __restrict__ ws_counts, const float* __restrict__ ws_sums,
    const double* __restrict__ ws_commit, float* __restrict__ out) {
  const int c = blockIdx.x;
  const int t = threadIdx.x;
  __shared__ float s_part[4];
  __shared__ float s_n;

  float nc[4];
  float psum = 0.f;
#pragma unroll
  for (int k = 0; k < 4; ++k) {
    int v = t + 256 * k;
    nc[k] = 0.99f * ema_count[c * VOCAB + v] + 0.01f * ws_counts[c * VOCAB + v];
    psum += nc[k];
  }
#pragma unroll
  for (int off = 32; off; off >>= 1) psum += __shfl_down(psum, off);
  if ((t & 63) == 0) s_part[t >> 6] = psum;
  __syncthreads();
  if (t == 0) s_n = (s_part[0] + s_part[1]) + (s_part[2] + s_part[3]);
  __syncthreads();
  const float nsum = s_n;
  const float veps = (float)(VOCAB * 1e-5);  // 0.01024f

#pragma unroll
  for (int k = 0; k < 4; ++k) {
    int v = t + 256 * k;
    float cnt = (nc[k] + 1e-5f) / (nsum + veps) * nsum;
    out[OFF_NCNT + c * VOCAB + v] = nc[k];
#pragma unroll
    for (int d = 0; d < 16; ++d) {
      size_t i = ((size_t)(c * VOCAB + v)) * CDIM + d;
      float nw = 0.99f * ema_weight[i] + 0.01f * ws_sums[i];
      out[OFF_NWT + i] = nw;
      out[OFF_NCB + i] = nw / cnt;
    }
  }
  if (c == 0 && t == 0)
    out[OFF_COMMIT] = (float)(*ws_commit / 1048576.0);
}

extern "C" void kernel_launch(void* const* d_in, const int* in_sizes, int n_in,
                              void* d_out, int out_size, void* d_ws,
                              size_t ws_size, hipStream_t stream) {
  const float* z = (const float*)d_in[0];
  const float* codebooks = (const float*)d_in[1];
  const float* ema_count = (const float*)d_in[2];
  const float* ema_weight = (const float*)d_in[3];
  float* out = (float*)d_out;

  float* wsf = (float*)d_ws;
  float* ws_counts = wsf + WS_COUNTS_OFF;
  float* ws_sums = wsf + WS_SUMS_OFF;
  double* ws_commit = (double*)((char*)d_ws + WS_COMMIT_BYTE_OFF);

  hipMemsetAsync(d_ws, 0, WS_ZERO_BYTES, stream);

  k_assign<<<dim3(256), dim3(256), 0, stream>>>(z, codebooks, out, ws_counts,
                                                ws_sums, ws_commit);
  k_update<<<dim3(8), dim3(256), 0, stream>>>(ema_count, ema_weight, ws_counts,
                                              ws_sums, ws_commit, out);
}

// Round 3
// 276.237 us; speedup vs baseline: 1.0031x; 1.0031x over previous
//
#include <hip/hip_runtime.h>

// SimVQuantizer: B=8, D=128 (N_CB=8 x CDIM=16), H=W=32 -> 8192 pixels.
// Outputs (FLOAT32, concatenated flat):
//   quantized  [8,128,32,32]  = 1048576   @ 0
//   indices    [8,8,32,32]    =   65536   @ 1048576
//   commitment scalar         =       1   @ 1114112
//   new_codebooks [8,1024,16] =  131072   @ 1114113
//   new_count  [8,1024]       =    8192   @ 1245185
//   new_weight [8,1024,16]    =  131072   @ 1253377

#define NCB   8
#define VOCAB 1024
#define CDIM  16
#define NPIX  8192   // B*H*W
#define HW    1024   // H*W

#define OFF_QUANT  0
#define OFF_IDX    1048576
#define OFF_COMMIT 1114112
#define OFF_NCB    1114113
#define OFF_NCNT   1245185
#define OFF_NWT    1253377

#define SLICES 8     // vocab slices per pixel (one wave each)
#define VPS    128   // vocab entries per slice
#define PPB    64    // pixels per block (= lanes of a wave)

// workspace layout (floats): counts[8*1024], sums[8*1024*16], then a double
#define WS_COUNTS_OFF 0
#define WS_SUMS_OFF   (NCB * VOCAB)
#define WS_COMMIT_BYTE_OFF (size_t)((NCB * VOCAB) * 4 + (NCB * VOCAB * CDIM) * 4) // 557056
#define WS_ZERO_BYTES (WS_COMMIT_BYTE_OFF + 8)

// numpy pairwise_sum (order-preserving 8-accumulator) for n=16:
// r[j] = a[j] + a[j+8];  res = ((r0+r1)+(r2+r3)) + ((r4+r5)+(r6+r7))
__device__ __forceinline__ float npsum16(const float m[16]) {
#pragma clang fp contract(off)
  float r0 = m[0] + m[8];
  float r1 = m[1] + m[9];
  float r2 = m[2] + m[10];
  float r3 = m[3] + m[11];
  float r4 = m[4] + m[12];
  float r5 = m[5] + m[13];
  float r6 = m[6] + m[14];
  float r7 = m[7] + m[15];
  return ((r0 + r1) + (r2 + r3)) + ((r4 + r5) + (r6 + r7));
}

__device__ __forceinline__ float npsum16sq(const float a[16]) {
#pragma clang fp contract(off)
  float m[16];
#pragma unroll
  for (int d = 0; d < 16; ++d) m[d] = a[d] * a[d];
  return npsum16(m);
}

// numpy einsum (optimize=False) npyv contig order for n=16:
// l_j = (m_j + m_{j+4}) + (m_{j+8} + m_{j+12}); res = (l0+l1) + (l2+l3)
__device__ __forceinline__ float npeinsum16(const float a[16], const float b[16]) {
#pragma clang fp contract(off)
  float m[16];
#pragma unroll
  for (int d = 0; d < 16; ++d) m[d] = a[d] * b[d];
  float l0 = (m[0] + m[4]) + (m[8] + m[12]);
  float l1 = (m[1] + m[5]) + (m[9] + m[13]);
  float l2 = (m[2] + m[6]) + (m[10] + m[14]);
  float l3 = (m[3] + m[7]) + (m[11] + m[15]);
  return (l0 + l1) + (l2 + l3);
}

// 1024 blocks x 512 threads. Block: c = bx>>7, pchunk = bx&127 (64 pixels).
// Wave w (= t>>6) scans vocab slice [w*128, w*128+128) for all 64 pixels;
// lane (= t&63) is the pixel -> codebook loads wave-uniform, z/out coalesced.
__global__ __launch_bounds__(512, 8) void k_assign(
    const float* __restrict__ z, const float* __restrict__ cb,
    float* __restrict__ out, float* __restrict__ ws_counts,
    float* __restrict__ ws_sums, double* __restrict__ ws_commit) {
  __shared__ float s_c2[VOCAB];
  __shared__ float s_best[SLICES * PPB];
  __shared__ int s_bi[SLICES * PPB];

  const int c = blockIdx.x >> 7;
  const int pchunk = blockIdx.x & 127;
  const int t = threadIdx.x;
  const int pix = t & 63;
  const int slice = t >> 6;

  const float* cbc = cb + (size_t)c * VOCAB * CDIM;

  // precompute ||cb||^2 into LDS (np.sum(cb*cb, -1), pairwise 8-acc order)
  for (int v = t; v < VOCAB; v += 512) {
    float e[16];
#pragma unroll
    for (int d = 0; d < 16; ++d) e[d] = cbc[(size_t)v * CDIM + d];
    s_c2[v] = npsum16sq(e);
  }
  __syncthreads();

  const int n = pchunk * PPB + pix;  // pixel id in [0, 8192)
  const int b = n >> 10;             // batch
  const int hw = n & 1023;           // h*W + w

  // zp[n,c,d] = z[b, c*16+d, h, w]; 64-lane coalesced per d
  const float* zbase = z + ((size_t)(b * 128 + c * 16)) * HW + hw;
  float zv[16];
#pragma unroll
  for (int d = 0; d < 16; ++d) zv[d] = zbase[(size_t)d * HW];

  const float z2 = npsum16sq(zv);

  float best = INFINITY;
  int bi = 0;
  const int v0 = slice * VPS;
#pragma unroll 4
  for (int vo = 0; vo < VPS; ++vo) {
    const int v = v0 + vo;
    float e[16];
    const float4* e4 = reinterpret_cast<const float4*>(cbc + (size_t)v * CDIM);
    float4 q0 = e4[0], q1 = e4[1], q2 = e4[2], q3 = e4[3];
    e[0] = q0.x; e[1] = q0.y; e[2] = q0.z; e[3] = q0.w;
    e[4] = q1.x; e[5] = q1.y; e[6] = q1.z; e[7] = q1.w;
    e[8] = q2.x; e[9] = q2.y; e[10] = q2.z; e[11] = q2.w;
    e[12] = q3.x; e[13] = q3.y; e[14] = q3.z; e[15] = q3.w;
    const float dot = npeinsum16(zv, e);
    float d2;
    {
#pragma clang fp contract(off)
      d2 = (z2 - 2.0f * dot) + s_c2[v];  // np order: (z2 - 2*einsum) + c2
    }
    const bool lt = d2 < best;  // strict: first index wins ties (np.argmin)
    best = lt ? d2 : best;
    bi = lt ? v : bi;
  }
  s_best[t] = best;
  s_bi[t] = bi;
  __syncthreads();

  // wave 0: combine 8 slice-minima in ascending slice order (strict < keeps
  // the lowest index among equal minima -> identical to sequential argmin),
  // then epilogue. Lane t already holds zv for pixel t.
  if (t < PPB) {
    best = s_best[t];
    bi = s_bi[t];
#pragma unroll
    for (int s = 1; s < SLICES; ++s) {
      const float ob = s_best[s * PPB + t];
      const int oi = s_bi[s * PPB + t];
      const bool lt = ob < best;
      best = lt ? ob : best;
      bi = lt ? oi : bi;
    }

    const float* qe = cbc + (size_t)bi * CDIM;
    float comm = 0.f;
#pragma unroll
    for (int d = 0; d < 16; ++d) {
      float zq = qe[d];
      float diff, qst;
      {
#pragma clang fp contract(off)
        diff = zv[d] - zq;
        qst = zv[d] + (zq - zv[d]);  // zq_st = zp + (zq - zp), as np computes
      }
      comm += diff * diff;
      out[OFF_QUANT + ((size_t)(b * 128 + c * 16 + d)) * HW + hw] = qst;
    }
    out[OFF_IDX + ((size_t)(b * NCB + c)) * HW + hw] = (float)bi;

    atomicAdd(&ws_counts[c * VOCAB + bi], 1.0f);
#pragma unroll
    for (int d = 0; d < 16; ++d)
      atomicAdd(&ws_sums[((size_t)(c * VOCAB + bi)) * CDIM + d], zv[d]);

    // commitment: reduce across the 64 lanes of wave 0, one f64 atomic/block
#pragma unroll
    for (int off = 32; off; off >>= 1) comm += __shfl_down(comm, off);
    if (t == 0) atomicAdd(ws_commit, (double)comm);
  }
}

// EMA update + Laplace-smoothed normalization. 8 blocks x 1024 threads.
__global__ __launch_bounds__(1024) void k_update(
    const float* __restrict__ ema_count, const float* __restrict__ ema_weight,
    const float* __restrict__ ws_counts, const float* __restrict__ ws_sums,
    const double* __restrict__ ws_commit, float* __restrict__ out) {
  const int c = blockIdx.x;
  const int t = threadIdx.x;  // = vocab entry v
  __shared__ float s_cnt[VOCAB];
  __shared__ float s_red[16];

  const float nc =
      0.99f * ema_count[c * VOCAB + t] + 0.01f * ws_counts[c * VOCAB + t];
  out[OFF_NCNT + c * VOCAB + t] = nc;

  float psum = nc;
#pragma unroll
  for (int off = 32; off; off >>= 1) psum += __shfl_down(psum, off);
  if ((t & 63) == 0) s_red[t >> 6] = psum;
  __syncthreads();
  if (t == 0) {
    float ns = 0.f;
#pragma unroll
    for (int i = 0; i < 16; ++i) ns += s_red[i];
    s_red[0] = ns;
  }
  __syncthreads();
  const float nsum = s_red[0];
  const float veps = 0.01024f;  // VOCAB * 1e-5

  s_cnt[t] = (nc + 1e-5f) / (nsum + veps) * nsum;
  __syncthreads();

#pragma unroll
  for (int k = 0; k < 16; ++k) {
    const int i = k * 1024 + t;  // element within codebook c, [0, 16384)
    const size_t gi = (size_t)c * VOCAB * CDIM + i;
    const float nw = 0.99f * ema_weight[gi] + 0.01f * ws_sums[gi];
    out[OFF_NWT + gi] = nw;
    out[OFF_NCB + gi] = nw / s_cnt[i >> 4];
  }
  if (c == 0 && t == 0)
    out[OFF_COMMIT] = (float)(*ws_commit / 1048576.0);
}

extern "C" void kernel_launch(void* const* d_in, const int* in_sizes, int n_in,
                              void* d_out, int out_size, void* d_ws,
                              size_t ws_size, hipStream_t stream) {
  const float* z = (const float*)d_in[0];
  const float* codebooks = (const float*)d_in[1];
  const float* ema_count = (const float*)d_in[2];
  const float* ema_weight = (const float*)d_in[3];
  float* out = (float*)d_out;

  float* wsf = (float*)d_ws;
  float* ws_counts = wsf + WS_COUNTS_OFF;
  float* ws_sums = wsf + WS_SUMS_OFF;
  double* ws_commit = (double*)((char*)d_ws + WS_COMMIT_BYTE_OFF);

  hipMemsetAsync(d_ws, 0, WS_ZERO_BYTES, stream);

  k_assign<<<dim3(1024), dim3(512), 0, stream>>>(z, codebooks, out, ws_counts,
                                                 ws_sums, ws_commit);
  k_update<<<dim3(8), dim3(1024), 0, stream>>>(ema_count, ema_weight,
                                               ws_counts, ws_sums, ws_commit,
                                               out);
}

// Round 4
// 207.509 us; speedup vs baseline: 1.3354x; 1.3312x over previous
//
#include <hip/hip_runtime.h>

// SimVQuantizer: B=8, D=128 (N_CB=8 x CDIM=16), H=W=32 -> 8192 pixels.
// Outputs (FLOAT32, concatenated flat):
//   quantized  [8,128,32,32]  = 1048576   @ 0
//   indices    [8,8,32,32]    =   65536   @ 1048576
//   commitment scalar         =       1   @ 1114112
//   new_codebooks [8,1024,16] =  131072   @ 1114113
//   new_count  [8,1024]       =    8192   @ 1245185
//   new_weight [8,1024,16]    =  131072   @ 1253377

#define NCB   8
#define VOCAB 1024
#define CDIM  16
#define NPIX  8192   // B*H*W
#define HW    1024   // H*W

#define OFF_QUANT  0
#define OFF_IDX    1048576
#define OFF_COMMIT 1114112
#define OFF_NCB    1114113
#define OFF_NCNT   1245185
#define OFF_NWT    1253377

// workspace layout (floats): counts[8*1024], sums[8*1024*16], then a double
#define WS_COUNTS_OFF 0
#define WS_SUMS_OFF   (NCB * VOCAB)
#define WS_COMMIT_BYTE_OFF (size_t)((NCB * VOCAB) * 4 + (NCB * VOCAB * CDIM) * 4) // 557056
#define WS_ZERO_BYTES (WS_COMMIT_BYTE_OFF + 8)

// numpy pairwise_sum (order-preserving 8-accumulator) for n=16:
// r[j] = a[j] + a[j+8];  res = ((r0+r1)+(r2+r3)) + ((r4+r5)+(r6+r7))
__device__ __forceinline__ float npsum16(const float m[16]) {
#pragma clang fp contract(off)
  float r0 = m[0] + m[8];
  float r1 = m[1] + m[9];
  float r2 = m[2] + m[10];
  float r3 = m[3] + m[11];
  float r4 = m[4] + m[12];
  float r5 = m[5] + m[13];
  float r6 = m[6] + m[14];
  float r7 = m[7] + m[15];
  return ((r0 + r1) + (r2 + r3)) + ((r4 + r5) + (r6 + r7));
}

__device__ __forceinline__ float npsum16sq(const float a[16]) {
#pragma clang fp contract(off)
  float m[16];
#pragma unroll
  for (int d = 0; d < 16; ++d) m[d] = a[d] * a[d];
  return npsum16(m);
}

// numpy einsum (optimize=False) npyv contig order for n=16:
// l_j = (m_j + m_{j+4}) + (m_{j+8} + m_{j+12}); res = (l0+l1) + (l2+l3)
__device__ __forceinline__ float npeinsum16(const float a[16], const float b[16]) {
#pragma clang fp contract(off)
  float m[16];
#pragma unroll
  for (int d = 0; d < 16; ++d) m[d] = a[d] * b[d];
  float l0 = (m[0] + m[4]) + (m[8] + m[12]);
  float l1 = (m[1] + m[5]) + (m[9] + m[13]);
  float l2 = (m[2] + m[6]) + (m[10] + m[14]);
  float l3 = (m[3] + m[7]) + (m[11] + m[15]);
  return (l0 + l1) + (l2 + l3);
}

// 1024 blocks x 512 threads. Block: c = bx>>7, pchunk = bx&127 (64 pixels).
// Lane (t&63) = pixel. Wave w = t>>6. Codebook is staged into LDS in two
// 32KB phases (512 entries each); in phase p wave w scans entries
// [p*512 + w*64, p*512 + w*64 + 64) via wave-uniform ds_read_b128 (broadcast).
// LDS total 40KB -> 4 blocks/CU -> 32 waves/CU (100% occupancy cap).
__global__ __launch_bounds__(512, 8) void k_assign(
    const float* __restrict__ z, const float* __restrict__ cb,
    float* __restrict__ out, float* __restrict__ ws_counts,
    float* __restrict__ ws_sums, double* __restrict__ ws_commit) {
  __shared__ float s_cb[512 * CDIM];   // 32KB: current phase's 512 entries
  __shared__ float s_c2[VOCAB];        // 4KB
  __shared__ float s_best[8 * 64];     // 2KB
  __shared__ int s_bi[8 * 64];         // 2KB

  const int c = blockIdx.x >> 7;
  const int pchunk = blockIdx.x & 127;
  const int t = threadIdx.x;
  const int pix = t & 63;
  const int w = t >> 6;

  const float* cbc = cb + (size_t)c * VOCAB * CDIM;
  const float4* cb4 = reinterpret_cast<const float4*>(cbc);
  float4* s_cb4 = reinterpret_cast<float4*>(s_cb);

  // ||cb||^2 for all 1024 entries (np.sum(cb*cb,-1), pairwise 8-acc order)
  for (int v = t; v < VOCAB; v += 512) {
    float e[16];
#pragma unroll
    for (int d = 0; d < 16; ++d) e[d] = cbc[(size_t)v * CDIM + d];
    s_c2[v] = npsum16sq(e);
  }

  const int n = pchunk * 64 + pix;  // pixel id in [0, 8192)
  const int b = n >> 10;            // batch
  const int hw = n & 1023;          // h*W + w

  // zp[n,c,d] = z[b, c*16+d, h, w]; 64-lane coalesced per d
  const float* zbase = z + ((size_t)(b * 128 + c * 16)) * HW + hw;
  float zv[16];
#pragma unroll
  for (int d = 0; d < 16; ++d) zv[d] = zbase[(size_t)d * HW];

  const float z2 = npsum16sq(zv);

  float best = INFINITY;
  int bi = 0;

  for (int p = 0; p < 2; ++p) {
    __syncthreads();  // p=0: c2 done; p=1: all readers done with s_cb
    // stage 512 entries (32KB) into LDS: 4 float4 per thread, coalesced
#pragma unroll
    for (int k = 0; k < 4; ++k) {
      const int i = k * 512 + t;
      s_cb4[i] = cb4[p * 2048 + i];
    }
    __syncthreads();

    const float4* sl4 = s_cb4 + w * 256;  // wave's 64 entries (wave-uniform)
    const int vbase = p * 512 + w * 64;
#pragma unroll 2
    for (int vo = 0; vo < 64; ++vo) {
      float e[16];
      float4 q0 = sl4[vo * 4 + 0], q1 = sl4[vo * 4 + 1];
      float4 q2 = sl4[vo * 4 + 2], q3 = sl4[vo * 4 + 3];
      e[0] = q0.x; e[1] = q0.y; e[2] = q0.z; e[3] = q0.w;
      e[4] = q1.x; e[5] = q1.y; e[6] = q1.z; e[7] = q1.w;
      e[8] = q2.x; e[9] = q2.y; e[10] = q2.z; e[11] = q2.w;
      e[12] = q3.x; e[13] = q3.y; e[14] = q3.z; e[15] = q3.w;
      const float dot = npeinsum16(zv, e);
      float d2;
      {
#pragma clang fp contract(off)
        d2 = (z2 - 2.0f * dot) + s_c2[vbase + vo];  // np: (z2-2*einsum)+c2
      }
      const bool lt = d2 < best;  // strict: ascending scan -> first-wins
      best = lt ? d2 : best;
      bi = lt ? (vbase + vo) : bi;
    }
  }
  s_best[w * 64 + pix] = best;
  s_bi[w * 64 + pix] = bi;
  __syncthreads();

  // wave 0: combine the 8 per-wave candidates. Wave sets interleave, so
  // break float ties by lower index -> exactly np.argmin's first-wins.
  if (t < 64) {
    best = s_best[t];
    bi = s_bi[t];
#pragma unroll
    for (int s = 1; s < 8; ++s) {
      const float ob = s_best[s * 64 + t];
      const int oi = s_bi[s * 64 + t];
      const bool take = (ob < best) || (ob == best && oi < bi);
      best = take ? ob : best;
      bi = take ? oi : bi;
    }

    // gather winning entry (from global; L2-hot), write outputs
    const float* qe = cbc + (size_t)bi * CDIM;
    float comm = 0.f;
#pragma unroll
    for (int d = 0; d < 16; ++d) {
      float zq = qe[d];
      float diff, qst;
      {
#pragma clang fp contract(off)
        diff = zv[d] - zq;
        qst = zv[d] + (zq - zv[d]);  // zq_st = zp + (zq - zp), as np computes
      }
      comm += diff * diff;
      out[OFF_QUANT + ((size_t)(b * 128 + c * 16 + d)) * HW + hw] = qst;
    }
    out[OFF_IDX + ((size_t)(b * NCB + c)) * HW + hw] = (float)bi;

    atomicAdd(&ws_counts[c * VOCAB + bi], 1.0f);
#pragma unroll
    for (int d = 0; d < 16; ++d)
      atomicAdd(&ws_sums[((size_t)(c * VOCAB + bi)) * CDIM + d], zv[d]);

    // commitment: reduce across wave 0's 64 lanes, one f64 atomic per block
#pragma unroll
    for (int off = 32; off; off >>= 1) comm += __shfl_down(comm, off);
    if (t == 0) atomicAdd(ws_commit, (double)comm);
  }
}

// EMA update + Laplace-smoothed normalization. 64 blocks x 256 threads:
// block = (c, part); every block recomputes its c's nsum (L2-cached reads),
// then writes a coalesced 1/8 slice of the outputs.
__global__ __launch_bounds__(256) void k_update(
    const float* __restrict__ ema_count, const float* __restrict__ ema_weight,
    const float* __restrict__ ws_counts, const float* __restrict__ ws_sums,
    const double* __restrict__ ws_commit, float* __restrict__ out) {
  const int c = blockIdx.x >> 3;
  const int part = blockIdx.x & 7;
  const int t = threadIdx.x;
  __shared__ float s_red[4];
  __shared__ float s_n;

  float psum = 0.f;
#pragma unroll
  for (int k = 0; k < 4; ++k) {
    const int v = k * 256 + t;
    psum += 0.99f * ema_count[c * VOCAB + v] + 0.01f * ws_counts[c * VOCAB + v];
  }
#pragma unroll
  for (int off = 32; off; off >>= 1) psum += __shfl_down(psum, off);
  if ((t & 63) == 0) s_red[t >> 6] = psum;
  __syncthreads();
  if (t == 0) s_n = (s_red[0] + s_red[1]) + (s_red[2] + s_red[3]);
  __syncthreads();
  const float nsum = s_n;
  const float veps = 0.01024f;  // VOCAB * 1e-5

  // new_count: 128 entries per block
  if (t < 128) {
    const int v = part * 128 + t;
    out[OFF_NCNT + c * VOCAB + v] =
        0.99f * ema_count[c * VOCAB + v] + 0.01f * ws_counts[c * VOCAB + v];
  }

  // new_weight / new_codebooks: 2048 elements per block, coalesced
#pragma unroll
  for (int k = 0; k < 8; ++k) {
    const int i = part * 2048 + k * 256 + t;  // element within codebook c
    const int v = i >> 4;
    const float nc =
        0.99f * ema_count[c * VOCAB + v] + 0.01f * ws_counts[c * VOCAB + v];
    const float cnt = (nc + 1e-5f) / (nsum + veps) * nsum;
    const size_t gi = (size_t)c * VOCAB * CDIM + i;
    const float nw = 0.99f * ema_weight[gi] + 0.01f * ws_sums[gi];
    out[OFF_NWT + gi] = nw;
    out[OFF_NCB + gi] = nw / cnt;
  }
  if (blockIdx.x == 0 && t == 0)
    out[OFF_COMMIT] = (float)(*ws_commit / 1048576.0);
}

extern "C" void kernel_launch(void* const* d_in, const int* in_sizes, int n_in,
                              void* d_out, int out_size, void* d_ws,
                              size_t ws_size, hipStream_t stream) {
  const float* z = (const float*)d_in[0];
  const float* codebooks = (const float*)d_in[1];
  const float* ema_count = (const float*)d_in[2];
  const float* ema_weight = (const float*)d_in[3];
  float* out = (float*)d_out;

  float* wsf = (float*)d_ws;
  float* ws_counts = wsf + WS_COUNTS_OFF;
  float* ws_sums = wsf + WS_SUMS_OFF;
  double* ws_commit = (double*)((char*)d_ws + WS_COMMIT_BYTE_OFF);

  hipMemsetAsync(d_ws, 0, WS_ZERO_BYTES, stream);

  k_assign<<<dim3(1024), dim3(512), 0, stream>>>(z, codebooks, out, ws_counts,
                                                 ws_sums, ws_commit);
  k_update<<<dim3(64), dim3(256), 0, stream>>>(ema_count, ema_weight,
                                               ws_counts, ws_sums, ws_commit,
                                               out);
}